// Round 1
// baseline (128.741 us; speedup 1.0000x reference)
//
#include <hip/hip_runtime.h>

// SKA: per-pixel dynamic grouped 3x3 conv.
// x: [B=16, C=128, H=56, W=56] f32
// w: [B=16, Cw=16, 9, H=56, W=56] f32   (channel c uses weight channel c % 16)
// out[b,c,h,w] = sum_{i,j in 0..2} xpad[b,c,h+i,w+j] * w[b, c%16, i*3+j, h, w]
// pad = 1 (zero padding).

#define SKA_B   16
#define SKA_C   128
#define SKA_CW  16
#define SKA_H   56
#define SKA_W   56
#define SKA_HW  (SKA_H * SKA_W)        // 3136
#define SKA_G   (SKA_C / SKA_CW)       // 8 groups sharing each weight channel

__global__ __launch_bounds__(256) void ska_kernel(
    const float* __restrict__ x,
    const float* __restrict__ w,
    float* __restrict__ out)
{
    const int tid = blockIdx.x * blockDim.x + threadIdx.x;
    // One thread per (b, cw, hw); it produces 8 outputs (one per group).
    const int hw  = tid % SKA_HW;
    const int bcw = tid / SKA_HW;
    const int cw  = bcw % SKA_CW;
    const int b   = bcw / SKA_CW;
    if (b >= SKA_B) return;

    const int h  = hw / SKA_W;
    const int ww = hw - h * SKA_W;

    // Load the 9 per-pixel weights once; they are shared by 8 channels.
    const float* wp = w + ((size_t)(b * SKA_CW + cw) * 9) * SKA_HW + hw;
    float wk[9];
#pragma unroll
    for (int k = 0; k < 9; ++k) wk[k] = wp[(size_t)k * SKA_HW];

    // Per-tap validity (zero padding at borders).
    const bool hv0 = (h - 1) >= 0;
    const bool hv2 = (h + 1) < SKA_H;
    const bool wv0 = (ww - 1) >= 0;
    const bool wv2 = (ww + 1) < SKA_W;

    const float* xb = x   + ((size_t)b * SKA_C + cw) * SKA_HW;  // channel cw of batch b
    float*       ob = out + ((size_t)b * SKA_C + cw) * SKA_HW + hw;

#pragma unroll
    for (int g = 0; g < SKA_G; ++g) {
        const float* xc = xb + (size_t)g * SKA_CW * SKA_HW + hw;  // center pixel
        float acc = 0.0f;

        // Row h-1
        if (hv0) {
            if (wv0) acc += xc[-SKA_W - 1] * wk[0];
                     acc += xc[-SKA_W    ] * wk[1];
            if (wv2) acc += xc[-SKA_W + 1] * wk[2];
        }
        // Row h
        {
            if (wv0) acc += xc[-1] * wk[3];
                     acc += xc[ 0] * wk[4];
            if (wv2) acc += xc[ 1] * wk[5];
        }
        // Row h+1
        if (hv2) {
            if (wv0) acc += xc[SKA_W - 1] * wk[6];
                     acc += xc[SKA_W    ] * wk[7];
            if (wv2) acc += xc[SKA_W + 1] * wk[8];
        }

        ob[(size_t)g * SKA_CW * SKA_HW] = acc;
    }
}

extern "C" void kernel_launch(void* const* d_in, const int* in_sizes, int n_in,
                              void* d_out, int out_size, void* d_ws, size_t ws_size,
                              hipStream_t stream) {
    const float* x = (const float*)d_in[0];
    const float* w = (const float*)d_in[1];
    float* out = (float*)d_out;

    const int total_threads = SKA_B * SKA_CW * SKA_HW;  // 802,816
    const int block = 256;
    const int grid = (total_threads + block - 1) / block;  // 3136

    ska_kernel<<<grid, block, 0, stream>>>(x, w, out);
}

// Round 2
// 106.874 us; speedup vs baseline: 1.2046x; 1.2046x over previous
//
#include <hip/hip_runtime.h>

// SKA: per-pixel dynamic grouped 3x3 conv, vectorized 4-wide along W.
// x: [B=16, C=128, H=56, W=56] f32
// w: [B=16, Cw=16, 9, H=56, W=56] f32   (channel c uses weight channel c % 16)
// out[b,c,h,w] = sum_{i,j} xpad[b,c,h+i,w+j] * w[b, c%16, i*3+j, h, w], pad=1.

#define SKA_B   16
#define SKA_C   128
#define SKA_CW  16
#define SKA_H   56
#define SKA_W   56
#define SKA_HW  (SKA_H * SKA_W)        // 3136
#define SKA_G   (SKA_C / SKA_CW)       // 8
#define SKA_Q   (SKA_W / 4)            // 14 float4 chunks per row

__global__ __launch_bounds__(256) void ska_kernel(
    const float* __restrict__ x,
    const float* __restrict__ w,
    float* __restrict__ out)
{
    const int tid = blockIdx.x * 256 + threadIdx.x;
    // tid -> (b, cw, h, q); consecutive tids walk q then h: fully contiguous
    // float4 address streams for w loads, x center loads, and out stores.
    const int q  = tid % SKA_Q;
    int t        = tid / SKA_Q;
    const int h  = t % SKA_H;
    t            = t / SKA_H;
    const int cw = t % SKA_CW;
    const int b  = t / SKA_CW;
    // grid is exact: 16*16*56*14 = 200704 = 784 * 256

    const int col = q * 4;
    const int hw  = h * SKA_W + col;

    // 9 per-pixel weight vectors, shared by 8 channels. All 16B-aligned.
    const float* wp = w + ((size_t)(b * SKA_CW + cw) * 9) * SKA_HW + hw;
    float4 wk[9];
#pragma unroll
    for (int k = 0; k < 9; ++k) wk[k] = *(const float4*)(wp + (size_t)k * SKA_HW);

    const bool hv0 = (h > 0);
    const bool hv2 = (h < SKA_H - 1);
    const bool lv  = (q > 0);
    const bool rv  = (q < SKA_Q - 1);

    const float* xb = x   + ((size_t)b * SKA_C + cw) * SKA_HW + hw;
    float*       ob = out + ((size_t)b * SKA_C + cw) * SKA_HW + hw;

#pragma unroll
    for (int g = 0; g < SKA_G; ++g) {
        const float* xc = xb + (size_t)g * SKA_CW * SKA_HW;
        float acc0 = 0.f, acc1 = 0.f, acc2 = 0.f, acc3 = 0.f;

#pragma unroll
        for (int r = 0; r < 3; ++r) {
            if (r == 0 && !hv0) continue;
            if (r == 2 && !hv2) continue;
            const float* xr = xc + (r - 1) * SKA_W;
            const float4 m = *(const float4*)xr;           // cols [col, col+3], aligned
            const float  L = lv ? xr[-1] : 0.0f;           // col-1
            const float  R = rv ? xr[4]  : 0.0f;           // col+4
            const float4 w0 = wk[3 * r + 0];
            const float4 w1 = wk[3 * r + 1];
            const float4 w2 = wk[3 * r + 2];
            acc0 += L   * w0.x + m.x * w1.x + m.y * w2.x;
            acc1 += m.x * w0.y + m.y * w1.y + m.z * w2.y;
            acc2 += m.y * w0.z + m.z * w1.z + m.w * w2.z;
            acc3 += m.z * w0.w + m.w * w1.w + R   * w2.w;
        }

        float4 o;
        o.x = acc0; o.y = acc1; o.z = acc2; o.w = acc3;
        *(float4*)(ob + (size_t)g * SKA_CW * SKA_HW) = o;
    }
}

extern "C" void kernel_launch(void* const* d_in, const int* in_sizes, int n_in,
                              void* d_out, int out_size, void* d_ws, size_t ws_size,
                              hipStream_t stream) {
    const float* x = (const float*)d_in[0];
    const float* w = (const float*)d_in[1];
    float* out = (float*)d_out;

    const int total_threads = SKA_B * SKA_CW * SKA_H * SKA_Q;  // 200704
    const int block = 256;
    const int grid = total_threads / block;                    // 784

    ska_kernel<<<grid, block, 0, stream>>>(x, w, out);
}